// Round 1
// baseline (81.192 us; speedup 1.0000x reference)
//
#include <hip/hip_runtime.h>
#include <hip/hip_bf16.h>

#define NUM_TABLES 21
#define NUM_CATS   1000
#define EMB_DIM    16
#define CONCAT_DIM 344
#define OUT_DIM    32
#define NEG_SLOPE  0.01f

// ---------- helpers ----------
__device__ __forceinline__ unsigned short f32_to_bf16_rne(float f) {
    unsigned int u = __float_as_uint(f);
    unsigned int r = u + 0x7FFFu + ((u >> 16) & 1u);  // round to nearest even
    return (unsigned short)(r >> 16);
}
__device__ __forceinline__ float bf16_to_f32(unsigned short h) {
    return __uint_as_float(((unsigned int)h) << 16);
}
__device__ __forceinline__ float lrelu(float v) {
    return v >= 0.f ? v : NEG_SLOPE * v;
}

// ---------- kernel 1: precompute P[t][c][j] = tables[t,c,:] . W[j, 16t:16t+16] (bf16)
// also packs wt[k][j] = W[j][336+k] (f32) for coalesced loads in kernel 2.
__global__ void build_P(const float* __restrict__ tables,
                        const float* __restrict__ W,
                        unsigned short* __restrict__ P,
                        float* __restrict__ wt) {
    int idx = blockIdx.x * 256 + threadIdx.x;
    if (idx < NUM_TABLES * NUM_CATS * OUT_DIM) {
        int j = idx & 31;
        int c = (idx >> 5) % NUM_CATS;
        int t = idx / (NUM_CATS * OUT_DIM);
        const float* trow = tables + (size_t)(t * NUM_CATS + c) * EMB_DIM;
        const float* wrow = W + (size_t)j * CONCAT_DIM + t * EMB_DIM;
        float acc = 0.f;
        #pragma unroll
        for (int k = 0; k < EMB_DIM; ++k) acc = fmaf(trow[k], wrow[k], acc);
        P[idx] = f32_to_bf16_rne(acc);
    }
    if (blockIdx.x == 0 && threadIdx.x < 8 * OUT_DIM) {
        int k = threadIdx.x >> 5;
        int j = threadIdx.x & 31;
        wt[k * OUT_DIM + j] = W[(size_t)j * CONCAT_DIM + (CONCAT_DIM - 8) + k];
    }
}

// ---------- kernel 2: per row, sum 21 gathered P rows + cont branch, lrelu.
// 8 lanes per row; each lane owns 4 consecutive outputs (ushort4 / float4).
__global__ void fwd(const int* __restrict__ xcat,
                    const float* __restrict__ xcont,
                    const unsigned short* __restrict__ P,
                    const float* __restrict__ Wc,
                    const float* __restrict__ bc,
                    const float* __restrict__ bias,
                    const float* __restrict__ wt,
                    float* __restrict__ out,
                    int nrows) {
    int gtid = blockIdx.x * 256 + threadIdx.x;
    int row = gtid >> 3;
    if (row >= nrows) return;
    int l = gtid & 7;

    const int* cats = xcat + (size_t)row * NUM_TABLES;

    float4 acc = *reinterpret_cast<const float4*>(bias + l * 4);

    #pragma unroll
    for (int t = 0; t < NUM_TABLES; ++t) {
        int c = cats[t];  // same addr across the 8-lane group -> broadcast
        const unsigned short* p = P + ((size_t)(t * NUM_CATS + c) * OUT_DIM) + l * 4;
        ushort4 u = *reinterpret_cast<const ushort4*>(p);
        acc.x += bf16_to_f32(u.x);
        acc.y += bf16_to_f32(u.y);
        acc.z += bf16_to_f32(u.z);
        acc.w += bf16_to_f32(u.w);
    }

    float x = xcont[row];
    #pragma unroll
    for (int k = 0; k < 8; ++k) {
        float cv = lrelu(fmaf(x, Wc[k], bc[k]));
        float4 w = *reinterpret_cast<const float4*>(wt + k * OUT_DIM + l * 4);
        acc.x = fmaf(cv, w.x, acc.x);
        acc.y = fmaf(cv, w.y, acc.y);
        acc.z = fmaf(cv, w.z, acc.z);
        acc.w = fmaf(cv, w.w, acc.w);
    }

    acc.x = lrelu(acc.x);
    acc.y = lrelu(acc.y);
    acc.z = lrelu(acc.z);
    acc.w = lrelu(acc.w);

    *reinterpret_cast<float4*>(out + (size_t)row * OUT_DIM + l * 4) = acc;
}

// ---------- fallback (if ws too small): direct f32 compute, no P table.
__global__ void fwd_direct(const int* __restrict__ xcat,
                           const float* __restrict__ xcont,
                           const float* __restrict__ tables,
                           const float* __restrict__ Wc,
                           const float* __restrict__ bc,
                           const float* __restrict__ W,
                           const float* __restrict__ bias,
                           float* __restrict__ out,
                           int nrows) {
    int gtid = blockIdx.x * 256 + threadIdx.x;
    int row = gtid >> 3;
    if (row >= nrows) return;
    int l = gtid & 7;
    int j0 = l * 4;

    const int* cats = xcat + (size_t)row * NUM_TABLES;
    float acc[4];
    #pragma unroll
    for (int jj = 0; jj < 4; ++jj) acc[jj] = bias[j0 + jj];

    for (int t = 0; t < NUM_TABLES; ++t) {
        int c = cats[t];
        const float* e = tables + (size_t)(t * NUM_CATS + c) * EMB_DIM;
        #pragma unroll
        for (int k = 0; k < EMB_DIM; ++k) {
            float ev = e[k];
            #pragma unroll
            for (int jj = 0; jj < 4; ++jj)
                acc[jj] = fmaf(ev, W[(size_t)(j0 + jj) * CONCAT_DIM + t * EMB_DIM + k], acc[jj]);
        }
    }
    float x = xcont[row];
    #pragma unroll
    for (int k = 0; k < 8; ++k) {
        float cv = lrelu(fmaf(x, Wc[k], bc[k]));
        #pragma unroll
        for (int jj = 0; jj < 4; ++jj)
            acc[jj] = fmaf(cv, W[(size_t)(j0 + jj) * CONCAT_DIM + (CONCAT_DIM - 8) + k], acc[jj]);
    }
    #pragma unroll
    for (int jj = 0; jj < 4; ++jj)
        out[(size_t)row * OUT_DIM + j0 + jj] = lrelu(acc[jj]);
}

extern "C" void kernel_launch(void* const* d_in, const int* in_sizes, int n_in,
                              void* d_out, int out_size, void* d_ws, size_t ws_size,
                              hipStream_t stream) {
    const int*   xcat   = (const int*)d_in[0];
    const float* xcont  = (const float*)d_in[1];
    const float* tables = (const float*)d_in[2];
    const float* Wc     = (const float*)d_in[3];
    const float* bc     = (const float*)d_in[4];
    const float* W      = (const float*)d_in[5];
    const float* bias   = (const float*)d_in[6];
    float* out = (float*)d_out;

    int nrows = in_sizes[0] / NUM_TABLES;

    const size_t P_elems = (size_t)NUM_TABLES * NUM_CATS * OUT_DIM;  // 672000
    const size_t P_bytes = P_elems * sizeof(unsigned short);         // 1,344,000 (16B aligned)
    const size_t wt_off  = P_bytes;
    const size_t need    = wt_off + 8 * OUT_DIM * sizeof(float);

    long total_threads = (long)nrows * 8;
    int  blocks2 = (int)((total_threads + 255) / 256);

    if (ws_size >= need) {
        unsigned short* P = (unsigned short*)d_ws;
        float* wt = (float*)((char*)d_ws + wt_off);
        int blocks1 = (int)((P_elems + 255) / 256);
        build_P<<<blocks1, 256, 0, stream>>>(tables, W, P, wt);
        fwd<<<blocks2, 256, 0, stream>>>(xcat, xcont, P, Wc, bc, bias, wt, out, nrows);
    } else {
        fwd_direct<<<blocks2, 256, 0, stream>>>(xcat, xcont, tables, Wc, bc, W, bias, out, nrows);
    }
}

// Round 7
// 77.357 us; speedup vs baseline: 1.0496x; 1.0496x over previous
//
#include <hip/hip_runtime.h>
#include <hip/hip_bf16.h>

#define NUM_TABLES 21
#define NUM_CATS   1000
#define EMB_DIM    16
#define CONCAT_DIM 344
#define OUT_DIM    32
#define NEG_SLOPE  0.01f

#define ROWS_PER_BLOCK 32          // 256 threads, 8 lanes per row
#define CATS_PER_BLOCK (ROWS_PER_BLOCK * NUM_TABLES)  // 672 ints

typedef float f32x4 __attribute__((ext_vector_type(4)));

// ---------- helpers ----------
__device__ __forceinline__ unsigned short f32_to_bf16_rne(float f) {
    unsigned int u = __float_as_uint(f);
    unsigned int r = u + 0x7FFFu + ((u >> 16) & 1u);  // round to nearest even
    return (unsigned short)(r >> 16);
}
__device__ __forceinline__ float bf16_to_f32(unsigned short h) {
    return __uint_as_float(((unsigned int)h) << 16);
}
__device__ __forceinline__ float lrelu(float v) {
    return v >= 0.f ? v : NEG_SLOPE * v;
}

// ---------- kernel 1: precompute P[t][c][j] = tables[t,c,:] . W[j, 16t:16t+16] (bf16)
// also packs wt[k][j] = W[j][336+k] (f32) for coalesced loads in kernel 2.
__global__ void build_P(const float* __restrict__ tables,
                        const float* __restrict__ W,
                        unsigned short* __restrict__ P,
                        float* __restrict__ wt) {
    int idx = blockIdx.x * 256 + threadIdx.x;
    if (idx < NUM_TABLES * NUM_CATS * OUT_DIM) {
        int j = idx & 31;
        int c = (idx >> 5) % NUM_CATS;
        int t = idx / (NUM_CATS * OUT_DIM);
        const float* trow = tables + (size_t)(t * NUM_CATS + c) * EMB_DIM;
        const float* wrow = W + (size_t)j * CONCAT_DIM + t * EMB_DIM;
        float acc = 0.f;
        #pragma unroll
        for (int k = 0; k < EMB_DIM; ++k) acc = fmaf(trow[k], wrow[k], acc);
        P[idx] = f32_to_bf16_rne(acc);
    }
    if (blockIdx.x == 0 && threadIdx.x < 8 * OUT_DIM) {
        int k = threadIdx.x >> 5;
        int j = threadIdx.x & 31;
        wt[k * OUT_DIM + j] = W[(size_t)j * CONCAT_DIM + (CONCAT_DIM - 8) + k];
    }
}

// ---------- kernel 2 ----------
// 8 lanes per row; each lane owns 4 consecutive outputs.
// x_cat staged through LDS (coalesced); all 21 gathers issued before the
// accumulate phase so they overlap in flight. No nontemporal hints — they
// caused post-timing readback divergence (stale L2 lines) in R6.
__global__ void __launch_bounds__(256)
fwd(const int* __restrict__ xcat,
    const float* __restrict__ xcont,
    const unsigned short* __restrict__ P,
    const float* __restrict__ Wc,
    const float* __restrict__ bc,
    const float* __restrict__ bias,
    const float* __restrict__ wt,
    float* __restrict__ out,
    int nrows) {
    __shared__ int s_cats[CATS_PER_BLOCK];

    const int tid = threadIdx.x;
    const long blk_cat_base = (long)blockIdx.x * CATS_PER_BLOCK;
    const long total_cats = (long)nrows * NUM_TABLES;

    // coalesced stage of this block's 32 rows of categorical indices
    #pragma unroll
    for (int i = 0; i < 3; ++i) {
        int li = tid + i * 256;
        if (li < CATS_PER_BLOCK) {
            long g = blk_cat_base + li;
            if (g < total_cats)
                s_cats[li] = xcat[g];
        }
    }
    __syncthreads();

    const int row_local = tid >> 3;
    const int l = tid & 7;
    const int row = blockIdx.x * ROWS_PER_BLOCK + row_local;
    if (row >= nrows) return;

    // phase 1: offsets (LDS broadcast reads)
    int offs[NUM_TABLES];
    #pragma unroll
    for (int t = 0; t < NUM_TABLES; ++t) {
        int c = s_cats[row_local * NUM_TABLES + t];
        offs[t] = (t * NUM_CATS + c) * OUT_DIM + l * 4;
    }

    // phase 2: all gathers in flight
    ushort4 u[NUM_TABLES];
    #pragma unroll
    for (int t = 0; t < NUM_TABLES; ++t)
        u[t] = *reinterpret_cast<const ushort4*>(P + offs[t]);

    // phase 3: accumulate
    const float* bsrc = bias + l * 4;
    f32x4 acc = { bsrc[0], bsrc[1], bsrc[2], bsrc[3] };
    #pragma unroll
    for (int t = 0; t < NUM_TABLES; ++t) {
        acc.x += bf16_to_f32(u[t].x);
        acc.y += bf16_to_f32(u[t].y);
        acc.z += bf16_to_f32(u[t].z);
        acc.w += bf16_to_f32(u[t].w);
    }

    // continuous branch
    float x = xcont[row];
    #pragma unroll
    for (int k = 0; k < 8; ++k) {
        float cv = lrelu(fmaf(x, Wc[k], bc[k]));
        const float* w = wt + k * OUT_DIM + l * 4;
        acc.x = fmaf(cv, w[0], acc.x);
        acc.y = fmaf(cv, w[1], acc.y);
        acc.z = fmaf(cv, w[2], acc.z);
        acc.w = fmaf(cv, w[3], acc.w);
    }

    acc.x = lrelu(acc.x);
    acc.y = lrelu(acc.y);
    acc.z = lrelu(acc.z);
    acc.w = lrelu(acc.w);

    *reinterpret_cast<f32x4*>(out + (size_t)row * OUT_DIM + l * 4) = acc;
}

extern "C" void kernel_launch(void* const* d_in, const int* in_sizes, int n_in,
                              void* d_out, int out_size, void* d_ws, size_t ws_size,
                              hipStream_t stream) {
    const int*   xcat   = (const int*)d_in[0];
    const float* xcont  = (const float*)d_in[1];
    const float* tables = (const float*)d_in[2];
    const float* Wc     = (const float*)d_in[3];
    const float* bc     = (const float*)d_in[4];
    const float* W      = (const float*)d_in[5];
    const float* bias   = (const float*)d_in[6];
    float* out = (float*)d_out;

    int nrows = in_sizes[0] / NUM_TABLES;

    const size_t P_elems = (size_t)NUM_TABLES * NUM_CATS * OUT_DIM;  // 672000
    const size_t P_bytes = P_elems * sizeof(unsigned short);
    const size_t wt_off  = P_bytes;

    unsigned short* P = (unsigned short*)d_ws;
    float* wt = (float*)((char*)d_ws + wt_off);

    int blocks1 = (int)((P_elems + 255) / 256);
    build_P<<<blocks1, 256, 0, stream>>>(tables, W, P, wt);

    int blocks2 = (nrows + ROWS_PER_BLOCK - 1) / ROWS_PER_BLOCK;
    fwd<<<blocks2, 256, 0, stream>>>(xcat, xcont, P, Wc, bc, bias, wt, out, nrows);
}

// Round 10
// 74.091 us; speedup vs baseline: 1.0958x; 1.0441x over previous
//
#include <hip/hip_runtime.h>
#include <hip/hip_bf16.h>

#define NUM_TABLES 21
#define NUM_CATS   1000
#define EMB_DIM    16
#define CONCAT_DIM 344
#define OUT_DIM    32
#define NEG_SLOPE  0.01f

#define ROWS_PER_BLOCK 64          // 256 threads, 4 lanes per row
#define CATS_PER_BLOCK (ROWS_PER_BLOCK * NUM_TABLES)  // 1344 ints

typedef float f32x4 __attribute__((ext_vector_type(4)));

// ---------- helpers ----------
__device__ __forceinline__ unsigned short f32_to_bf16_rne(float f) {
    unsigned int u = __float_as_uint(f);
    unsigned int r = u + 0x7FFFu + ((u >> 16) & 1u);  // round to nearest even
    return (unsigned short)(r >> 16);
}
__device__ __forceinline__ float lrelu(float v) {
    return v >= 0.f ? v : NEG_SLOPE * v;
}

// ---------- kernel 1: precompute P[t][c][j] = tables[t,c,:] . W[j, 16t:16t+16] (bf16)
// also packs wt[k][j] = W[j][336+k] (f32) for coalesced loads in kernel 2.
__global__ void build_P(const float* __restrict__ tables,
                        const float* __restrict__ W,
                        unsigned short* __restrict__ P,
                        float* __restrict__ wt) {
    int idx = blockIdx.x * 256 + threadIdx.x;
    if (idx < NUM_TABLES * NUM_CATS * OUT_DIM) {
        int j = idx & 31;
        int c = (idx >> 5) % NUM_CATS;
        int t = idx / (NUM_CATS * OUT_DIM);
        const float* trow = tables + (size_t)(t * NUM_CATS + c) * EMB_DIM;
        const float* wrow = W + (size_t)j * CONCAT_DIM + t * EMB_DIM;
        float acc = 0.f;
        #pragma unroll
        for (int k = 0; k < EMB_DIM; ++k) acc = fmaf(trow[k], wrow[k], acc);
        P[idx] = f32_to_bf16_rne(acc);
    }
    if (blockIdx.x == 0 && threadIdx.x < 8 * OUT_DIM) {
        int k = threadIdx.x >> 5;
        int j = threadIdx.x & 31;
        wt[k * OUT_DIM + j] = W[(size_t)j * CONCAT_DIM + (CONCAT_DIM - 8) + k];
    }
}

// ---------- kernel 2 ----------
// 4 lanes per row; each lane owns 8 consecutive outputs (one dwordx4 gather
// of 8 bf16 per table). x_cat staged through LDS.
__global__ void __launch_bounds__(256, 4)
fwd(const int* __restrict__ xcat,
    const float* __restrict__ xcont,
    const unsigned short* __restrict__ P,
    const float* __restrict__ Wc,
    const float* __restrict__ bc,
    const float* __restrict__ bias,
    const float* __restrict__ wt,
    float* __restrict__ out,
    int nrows) {
    __shared__ int s_cats[CATS_PER_BLOCK];

    const int tid = threadIdx.x;
    const long blk_cat_base = (long)blockIdx.x * CATS_PER_BLOCK;
    const long total_cats = (long)nrows * NUM_TABLES;

    // coalesced stage of this block's 64 rows of categorical indices
    #pragma unroll
    for (int i = 0; i < 6; ++i) {
        int li = tid + i * 256;
        if (li < CATS_PER_BLOCK) {
            long g = blk_cat_base + li;
            if (g < total_cats) s_cats[li] = xcat[g];
        }
    }
    __syncthreads();

    const int row_local = tid >> 2;        // 0..63
    const int l = tid & 3;                 // lane-in-row, owns outputs l*8..l*8+7
    const int row = blockIdx.x * ROWS_PER_BLOCK + row_local;
    if (row >= nrows) return;

    // phase 1: offsets (LDS broadcast reads), in ushort units
    int offs[NUM_TABLES];
    #pragma unroll
    for (int t = 0; t < NUM_TABLES; ++t) {
        int c = s_cats[row_local * NUM_TABLES + t];
        offs[t] = (t * NUM_CATS + c) * OUT_DIM + l * 8;
    }

    // phase 2: gathers (16B each) — keep them batched so they pipeline
    uint4 u[NUM_TABLES];
    #pragma unroll
    for (int t = 0; t < NUM_TABLES; ++t)
        u[t] = *reinterpret_cast<const uint4*>(P + offs[t]);

    // phase 3: unpack-and-accumulate. word w holds elems (2k, 2k+1):
    // lo = w<<16, hi = w & 0xFFFF0000 (both are the f32 bit patterns).
    float acc[8];
    const float* bsrc = bias + l * 8;
    #pragma unroll
    for (int m = 0; m < 8; ++m) acc[m] = bsrc[m];

    #pragma unroll
    for (int t = 0; t < NUM_TABLES; ++t) {
        unsigned int w0 = u[t].x, w1 = u[t].y, w2 = u[t].z, w3 = u[t].w;
        acc[0] += __uint_as_float(w0 << 16);
        acc[1] += __uint_as_float(w0 & 0xFFFF0000u);
        acc[2] += __uint_as_float(w1 << 16);
        acc[3] += __uint_as_float(w1 & 0xFFFF0000u);
        acc[4] += __uint_as_float(w2 << 16);
        acc[5] += __uint_as_float(w2 & 0xFFFF0000u);
        acc[6] += __uint_as_float(w3 << 16);
        acc[7] += __uint_as_float(w3 & 0xFFFF0000u);
    }

    // continuous branch
    float x = xcont[row];
    #pragma unroll
    for (int k = 0; k < 8; ++k) {
        float cv = lrelu(fmaf(x, Wc[k], bc[k]));
        const float* w = wt + k * OUT_DIM + l * 8;
        #pragma unroll
        for (int m = 0; m < 8; ++m)
            acc[m] = fmaf(cv, w[m], acc[m]);
    }

    #pragma unroll
    for (int m = 0; m < 8; ++m) acc[m] = lrelu(acc[m]);

    float* orow = out + (size_t)row * OUT_DIM + l * 8;
    f32x4 lo = { acc[0], acc[1], acc[2], acc[3] };
    f32x4 hi = { acc[4], acc[5], acc[6], acc[7] };
    *reinterpret_cast<f32x4*>(orow)     = lo;
    *reinterpret_cast<f32x4*>(orow + 4) = hi;
}

extern "C" void kernel_launch(void* const* d_in, const int* in_sizes, int n_in,
                              void* d_out, int out_size, void* d_ws, size_t ws_size,
                              hipStream_t stream) {
    const int*   xcat   = (const int*)d_in[0];
    const float* xcont  = (const float*)d_in[1];
    const float* tables = (const float*)d_in[2];
    const float* Wc     = (const float*)d_in[3];
    const float* bc     = (const float*)d_in[4];
    const float* W      = (const float*)d_in[5];
    const float* bias   = (const float*)d_in[6];
    float* out = (float*)d_out;

    int nrows = in_sizes[0] / NUM_TABLES;

    const size_t P_elems = (size_t)NUM_TABLES * NUM_CATS * OUT_DIM;  // 672000
    const size_t P_bytes = P_elems * sizeof(unsigned short);
    const size_t wt_off  = P_bytes;

    unsigned short* P = (unsigned short*)d_ws;
    float* wt = (float*)((char*)d_ws + wt_off);

    int blocks1 = (int)((P_elems + 255) / 256);
    build_P<<<blocks1, 256, 0, stream>>>(tables, W, P, wt);

    int blocks2 = (nrows + ROWS_PER_BLOCK - 1) / ROWS_PER_BLOCK;
    fwd<<<blocks2, 256, 0, stream>>>(xcat, xcont, P, Wc, bc, bias, wt, out, nrows);
}